// Round 2
// 299.683 us; speedup vs baseline: 1.1189x; 1.1189x over previous
//
#include <hip/hip_runtime.h>
#include <hip/hip_bf16.h>

// Problem constants (all powers of two -> index math is shifts/masks)
#define B_   8
#define N_   16384
#define C_   128
#define OUT_ 256
#define E_   262144

// ws word layout (uint32 offsets). ws_size measured ~537 MB (round-4 fill
// counters), we need 68.4 MB.
//   [0,       16384)    : deg; memset 0 -> hist; scan rewrites as build cursors
//   [16384,   32769)    : offs exclusive prefix, offs[16384] = E
//   [32832,   294976)   : sorted_col (counting-sorted by row)
//   [294976,  311360)   : Wt bf16 [n][k] transposed weights (256x128)
//   [311360,  8699968)  : x_bf bf16 copy of x (B*N*C shorts)
//   [8699968, 17088576) : aggr bf16 (max_j x_j - x_i), row-major (b,row,c)
#define DEG_OFF  0u
#define OFFS_OFF 16384u
#define SCOL_OFF 32832u
#define WT_OFF   294976u
#define XBF_OFF  311360u
#define AGGR_OFF 8699968u

typedef __attribute__((ext_vector_type(8))) short bf16x8; // 8 bf16 = 4 VGPRs
typedef __attribute__((ext_vector_type(4))) float f32x4;

__device__ __forceinline__ unsigned short f2bf(float f) { // RNE, no NaN inputs
  unsigned u = __float_as_uint(f);
  u += 0x7FFFu + ((u >> 16) & 1u);
  return (unsigned short)(u >> 16);
}
__device__ __forceinline__ float gelu_exact(float v) {
  return 0.5f * v * (1.0f + erff(v * 0.70710678118654752f));
}

// ---------------- kernel 1: fused x->bf16 | deg histogram | Wt prep -------------
// Per-block dtype detect: odd u32 words are int64-highs (==0) or int32 index
// values (nonzero w.h.p.); 256 samples/block -> P(wrong) = 16384^-256 ~ 0.
__global__ __launch_bounds__(256) void k_fused1(const float* __restrict__ x,
                                                const unsigned* __restrict__ eidx,
                                                const float* __restrict__ W,
                                                unsigned* __restrict__ ws) {
  const unsigned bid = blockIdx.x, tid = threadIdx.x;
  if (bid < 16384u) { // ---- x fp32 -> bf16 packed (4,194,304 float4 slots)
    unsigned i = bid * 256u + tid;
    float4 v = ((const float4*)x)[i];
    uint2 o;
    o.x = (unsigned)f2bf(v.x) | ((unsigned)f2bf(v.y) << 16);
    o.y = (unsigned)f2bf(v.z) | ((unsigned)f2bf(v.w) << 16);
    ((uint2*)(ws + XBF_OFF))[i] = o;
  } else if (bid < 17408u) { // ---- degree histogram, one edge per thread
    __shared__ int flag32;
    if (tid == 0) flag32 = 0;
    __syncthreads();
    unsigned e = (bid - 16384u) * 256u + tid; // 0..262143
    if (eidx[2u * e + 1u] != 0u) flag32 = 1;  // benign race
    __syncthreads();
    int row = flag32 ? (int)eidx[e] : (int)((const long long*)eidx)[e];
    atomicAdd(ws + DEG_OFF + (unsigned)row, 1u);
  } else { // ---- W fp32 -> bf16 transposed (128 blocks)
    unsigned t = (bid - 17408u) * 256u + tid; // 0..32767
    unsigned n = t >> 7, k = t & 127u;
    ((unsigned short*)(ws + WT_OFF))[n * 128u + k] = f2bf(W[k * 256u + n]);
  }
}

// ---------------- kernel 2: exclusive scan (single block) -----------------------
__global__ __launch_bounds__(1024) void k_scan(unsigned* __restrict__ ws) {
  __shared__ unsigned part[1024];
  const unsigned t = threadIdx.x;
  unsigned* deg  = ws + DEG_OFF;
  unsigned* offs = ws + OFFS_OFF;
  unsigned v[16], s = 0;
#pragma unroll
  for (int j = 0; j < 16; ++j) { v[j] = deg[t * 16 + j]; s += v[j]; }
  part[t] = s;
  __syncthreads();
  for (int d = 1; d < 1024; d <<= 1) {
    unsigned add = (t >= (unsigned)d) ? part[t - d] : 0u;
    __syncthreads();
    part[t] += add;
    __syncthreads();
  }
  unsigned base = (t == 0u) ? 0u : part[t - 1];
#pragma unroll
  for (int j = 0; j < 16; ++j) {
    unsigned pv = v[j];
    offs[t * 16 + j] = base;
    deg[t * 16 + j] = base; // deg[] becomes the build cursor
    base += pv;
  }
  if (t == 1023u) offs[16384] = base; // == E
}

// ---------------- kernel 3: counting-sort edges by row --------------------------
__global__ __launch_bounds__(256) void k_build(const unsigned* __restrict__ eidx,
                                               unsigned* __restrict__ ws) {
  __shared__ int flag32;
  if (threadIdx.x == 0) flag32 = 0;
  __syncthreads();
  unsigned e = blockIdx.x * 256u + threadIdx.x;
  if (eidx[2u * e + 1u] != 0u) flag32 = 1;
  __syncthreads();
  int row, col;
  if (flag32) {
    row = (int)eidx[e];
    col = (int)eidx[e + E_];
  } else {
    const long long* p = (const long long*)eidx;
    row = (int)p[e];
    col = (int)p[e + E_];
  }
  unsigned pos = atomicAdd(ws + DEG_OFF + (unsigned)row, 1u);
  ws[SCOL_OFF + pos] = (unsigned)col;
}

// ---------------- kernel 4: full-row CSR gather-max, dwordx4 (bf16) -------------
// One wave per (batch,row). 64 lanes = 4 edge-groups x 16 lanes; each lane loads
// uint4 (8 channels) -> one wave-load gathers 4 edges x full 128-ch row (1 KB).
// Column list for the row (deg<=64 in practice, Poisson(16)) is pre-loaded into
// one register/lane and broadcast per-quad with __shfl (ds_bpermute) -> the
// serial scol->xb VMEM chain of the old kernel collapses to one level.
// EXEC HAZARD (R1 bug): ds_bpermute returns UNDEFINED data when the *source*
// lane is inactive -> every __shfl here must execute under full EXEC (outside
// divergent guards). All shuffles below are hoisted to wave-uniform code.
// batch = blockIdx&7 -> per-XCD gather slice = 4 MB x_bf (marginally over L2;
// overflow absorbed by L3). Max trick unchanged: fmax on raw u32 (hi channel;
// garbage low mantissa can't flip a bf16-level compare) and on u<<16 (lo, exact).
__global__ __launch_bounds__(256) void k_aggr4(const uint4* __restrict__ xbf4,
                                               const unsigned* __restrict__ ws,
                                               uint4* __restrict__ aggr4) {
  const unsigned bi = blockIdx.x;            // 32768 = 4096 rowgroups x 8 batches
  const unsigned b  = bi & 7u;
  const unsigned rg = bi >> 3;               // 0..4095
  const unsigned row = (rg << 2) | (threadIdx.x >> 6); // wave <-> row
  const unsigned lane = threadIdx.x & 63u;
  const unsigned g  = lane >> 4;             // edge subgroup 0..3
  const unsigned ln = lane & 15u;            // uint4 slot within the row
  const unsigned* offs = ws + OFFS_OFF;
  const unsigned* scol = ws + SCOL_OFF;
  const uint4* xb = xbf4 + ((size_t)b << 18); // rows stride 16 uint4

  const unsigned j0 = offs[row], e1 = offs[row + 1];
  const bool has = (j0 < e1);
  const unsigned deg = e1 - j0;
  const unsigned d64 = deg < 64u ? deg : 64u;

  // pre-load this row's first 64 columns (one coalesced load, reg-resident)
  unsigned cpre = 0u;
  if (has) {
    unsigned ci = j0 + lane;
    cpre = scol[ci < e1 ? ci : (e1 - 1u)];
  }

  float mlo[4], mhi[4];
#pragma unroll
  for (int r = 0; r < 4; ++r) { mlo[r] = -INFINITY; mhi[r] = -INFINITY; }

#define MAX1(a, r)                                                          \
  mhi[r] = fmaxf(mhi[r], __uint_as_float(a));                               \
  mlo[r] = fmaxf(mlo[r], __uint_as_float((a) << 16));
#define MAX2(a, c, r)                                                       \
  mhi[r] = fmaxf(mhi[r], fmaxf(__uint_as_float(a), __uint_as_float(c)));    \
  mlo[r] = fmaxf(mlo[r],                                                    \
      fmaxf(__uint_as_float((a) << 16), __uint_as_float((c) << 16)));

  unsigned t = 0u;
  while (t + 8u <= d64) { // 8 edges/iter: 2 independent 1KB gathers in flight
    // wave-uniform condition -> full EXEC for both shuffles (safe)
    unsigned c0 = (unsigned)__shfl((int)cpre, (int)(t + g));
    unsigned c1 = (unsigned)__shfl((int)cpre, (int)(t + 4u + g));
    uint4 u0 = xb[((size_t)c0 << 4) + ln];
    uint4 u1 = xb[((size_t)c1 << 4) + ln];
    MAX2(u0.x, u1.x, 0) MAX2(u0.y, u1.y, 1)
    MAX2(u0.z, u1.z, 2) MAX2(u0.w, u1.w, 3)
    t += 8u;
  }
  if (t + 4u <= d64) { // wave-uniform branch -> full EXEC (safe)
    unsigned c = (unsigned)__shfl((int)cpre, (int)(t + g));
    uint4 u = xb[((size_t)c << 4) + ln];
    MAX1(u.x, 0) MAX1(u.y, 1) MAX1(u.z, 2) MAX1(u.w, 3)
    t += 4u;
  }
  {
    // final partial quad (0..3 edges). Shuffle HOISTED out of the divergent
    // guard: under the guard, source lane t+g can sit in an inactive group and
    // ds_bpermute would return undefined data (the R1 correctness bug).
    unsigned rem = d64 - t; // 0..3, wave-uniform
    unsigned c = (unsigned)__shfl((int)cpre, (int)((t + g) & 63u));
    if (g < rem) {
      uint4 u = xb[((size_t)c << 4) + ln];
      MAX1(u.x, 0) MAX1(u.y, 1) MAX1(u.z, 2) MAX1(u.w, 3)
    }
  }
  // deg > 64 overflow path: P ~ 1e-51 for Poisson(16); correctness guard only.
  // Direct scol loads (no shuffle) -> divergence-safe.
  for (unsigned j = j0 + 64u; j < e1; j += 4u) {
    unsigned r2 = e1 - j;
    if (g < (r2 < 4u ? r2 : 4u)) {
      unsigned c = scol[j + g];
      uint4 u = xb[((size_t)c << 4) + ln];
      MAX1(u.x, 0) MAX1(u.y, 1) MAX1(u.z, 2) MAX1(u.w, 3)
    }
  }
#undef MAX1
#undef MAX2

  // reduce the 4 edge-groups (lane bits 4,5); full EXEC here (reconverged)
#pragma unroll
  for (int r = 0; r < 4; ++r) {
    mlo[r] = fmaxf(mlo[r], __shfl_xor(mlo[r], 16, 64));
    mhi[r] = fmaxf(mhi[r], __shfl_xor(mhi[r], 16, 64));
  }
#pragma unroll
  for (int r = 0; r < 4; ++r) {
    mlo[r] = fmaxf(mlo[r], __shfl_xor(mlo[r], 32, 64));
    mhi[r] = fmaxf(mhi[r], __shfl_xor(mhi[r], 32, 64));
  }

  if (g == 0u) {
    const uint4 xw = xb[((size_t)row << 4) + ln];
    unsigned xv[4] = {xw.x, xw.y, xw.z, xw.w};
    unsigned ox[4];
#pragma unroll
    for (int r = 0; r < 4; ++r) {
      float vlo = has ? mlo[r] : 0.0f;
      float vhi = has ? __uint_as_float(__float_as_uint(mhi[r]) & 0xFFFF0000u)
                      : 0.0f;
      unsigned lo = f2bf(vlo - __uint_as_float(xv[r] << 16));
      unsigned hi = f2bf(vhi - __uint_as_float(xv[r] & 0xFFFF0000u));
      ox[r] = lo | (hi << 16);
    }
    uint4 o = {ox[0], ox[1], ox[2], ox[3]};
    aggr4[(((size_t)b << 14) + row) * 16u + ln] = o;
  }
}

// ---------------- kernel 5: aggr(bf16) @ Wt(bf16) + b, exact GELU ---------------
// A-fragments read directly from global (no intra-block A reuse; the 4 unrolled
// kc loads cover full 64B lines per row). LDS = Wt only -> 4 blocks/CU.
__global__ __launch_bounds__(256, 4) void k_gemm(const unsigned short* __restrict__ aggr,
                                                 const unsigned short* __restrict__ Wt,
                                                 const float* __restrict__ bias,
                                                 float* __restrict__ out) {
  __shared__ unsigned short Wt_sm[128 * 136]; // 34816 B; stride 136 (2-way free)
  const int tid = threadIdx.x;
  const int nbase = blockIdx.x * 128; // n-tiles adjacent in dispatch: A re-read
  const int mbase = blockIdx.y * 64;  // of the same m-tile stays cache-warm

#pragma unroll
  for (int i = 0; i < 8; ++i) {
    int slot = i * 256 + tid;
    int n = slot >> 4, k8 = slot & 15;
    uint4 u = *(const uint4*)(Wt + (size_t)(nbase + n) * 128 + k8 * 8);
    *(uint4*)&Wt_sm[n * 136 + k8 * 8] = u;
  }
  __syncthreads();

  const int lane = tid & 63;
  const int wv = tid >> 6;   // wave id: rows [wv*16, wv*16+16)
  const int ln = lane & 15;
  const int q = lane >> 4;   // quad

  // A-operand: A[m = lane&15][k = quad*8 + j] -> 16B contiguous in global
  const unsigned short* arow = aggr + (size_t)(mbase + wv * 16 + ln) * 128 + q * 8;
  bf16x8 af[4];
#pragma unroll
  for (int kc = 0; kc < 4; ++kc) af[kc] = *(const bf16x8*)(arow + kc * 32);

  f32x4 acc[8];
#pragma unroll
  for (int f = 0; f < 8; ++f) acc[f] = (f32x4){0.f, 0.f, 0.f, 0.f};

#pragma unroll
  for (int kc = 0; kc < 4; ++kc) {
#pragma unroll
    for (int f = 0; f < 8; ++f) {
      // B-operand: B[k = quad*8 + j][n = lane&15] contiguous in Wt[n][k]
      bf16x8 bf = *(const bf16x8*)&Wt_sm[(f * 16 + ln) * 136 + kc * 32 + q * 8];
      acc[f] = __builtin_amdgcn_mfma_f32_16x16x32_bf16(af[kc], bf, acc[f], 0, 0, 0);
    }
  }

  // Epilogue: C/D layout col = lane&15, row = quad*4 + reg (m89-verified)
#pragma unroll
  for (int f = 0; f < 8; ++f) {
    int n = nbase + f * 16 + ln;
    float bv = bias[n];
#pragma unroll
    for (int r = 0; r < 4; ++r) {
      int m = mbase + wv * 16 + q * 4 + r;
      out[(size_t)m * 256 + n] = gelu_exact(acc[f][r] + bv);
    }
  }
}

extern "C" void kernel_launch(void* const* d_in, const int* in_sizes, int n_in,
                              void* d_out, int out_size, void* d_ws, size_t ws_size,
                              hipStream_t stream) {
  const float* x      = (const float*)d_in[0];
  const unsigned* eid = (const unsigned*)d_in[1];
  const float* W      = (const float*)d_in[2];
  const float* bia    = (const float*)d_in[3];
  float* out          = (float*)d_out;
  unsigned* ws        = (unsigned*)d_ws;

  unsigned short* Wt   = (unsigned short*)(ws + WT_OFF);
  unsigned short* aggr = (unsigned short*)(ws + AGGR_OFF);

  hipMemsetAsync(ws + DEG_OFF, 0, 16384 * sizeof(unsigned), stream);
  hipLaunchKernelGGL(k_fused1, dim3(17536),   dim3(256),  0, stream, x, eid, W, ws);
  hipLaunchKernelGGL(k_scan,   dim3(1),       dim3(1024), 0, stream, ws);
  hipLaunchKernelGGL(k_build,  dim3(1024),    dim3(256),  0, stream, eid, ws);
  hipLaunchKernelGGL(k_aggr4,  dim3(32768),   dim3(256),  0, stream,
                     (const uint4*)(ws + XBF_OFF), ws, (uint4*)(ws + AGGR_OFF));
  hipLaunchKernelGGL(k_gemm,   dim3(2, 2048), dim3(256),  0, stream,
                     aggr, Wt, bia, out);
}

// Round 3
// 284.531 us; speedup vs baseline: 1.1785x; 1.0533x over previous
//
#include <hip/hip_runtime.h>
#include <hip/hip_bf16.h>

// Problem constants (all powers of two -> index math is shifts/masks)
#define B_   8
#define N_   16384
#define C_   128
#define OUT_ 256
#define E_   262144

// ws word layout (uint32 offsets). ws_size ~537 MB, we use ~73.5 MB.
//   [0,        16384)    : cnt[row]; memset 0 -> per-row edge count (may exceed 64)
//   [16384,    16448)    : ovf_cnt (word 16384) + pad; memset covers it
//   [16448,    540736)   : overflow (row,col) pairs - correctness path only
//   [540736,   1589312)  : tab: fixed-capacity col table, 64 slots/row (16384*64)
//   [1589312,  1605696)  : Wt bf16 [n][k] transposed weights (256x128)
//   [1605696,  9994304)  : x_bf bf16 copy of x (B*N*C shorts)
//   [9994304,  18382912) : aggr bf16 (max_j x_j - x_i), row-major (b,row,c)
#define CNT_OFF  0u
#define OVFC_OFF 16384u
#define OVF_OFF  16448u
#define TAB_OFF  540736u
#define WT_OFF   1589312u
#define XBF_OFF  1605696u
#define AGGR_OFF 9994304u

typedef __attribute__((ext_vector_type(8))) short bf16x8; // 8 bf16 = 4 VGPRs
typedef __attribute__((ext_vector_type(4))) float f32x4;

__device__ __forceinline__ unsigned short f2bf(float f) { // RNE, no NaN inputs
  unsigned u = __float_as_uint(f);
  u += 0x7FFFu + ((u >> 16) & 1u);
  return (unsigned short)(u >> 16);
}
__device__ __forceinline__ float gelu_exact(float v) {
  return 0.5f * v * (1.0f + erff(v * 0.70710678118654752f));
}

// ------------- kernel 1: fused x->bf16 | direct edge-table build | Wt prep ------
// Counting sort (scan+build kernels) eliminated: aggr never needs column ORDER,
// only the set -> fixed-capacity table (64 slots/row) built in ONE edge pass with
// atomic cursors. Overflow rows (P ~ 1e-14 at Poisson(16) degrees) spill (row,col)
// pairs to a global list that aggr replays -> correct for ANY input.
// Per-block dtype detect: odd u32 words are int64-highs (==0) or int32 index
// values (nonzero w.h.p.); 256 samples/block -> P(wrong) = 16384^-256 ~ 0.
__global__ __launch_bounds__(256) void k_prep(const float* __restrict__ x,
                                              const unsigned* __restrict__ eidx,
                                              const float* __restrict__ W,
                                              unsigned* __restrict__ ws) {
  const unsigned bid = blockIdx.x, tid = threadIdx.x;
  if (bid < 16384u) { // ---- x fp32 -> bf16 packed (4,194,304 float4 slots)
    unsigned i = bid * 256u + tid;
    float4 v = ((const float4*)x)[i];
    uint2 o;
    o.x = (unsigned)f2bf(v.x) | ((unsigned)f2bf(v.y) << 16);
    o.y = (unsigned)f2bf(v.z) | ((unsigned)f2bf(v.w) << 16);
    ((uint2*)(ws + XBF_OFF))[i] = o;
  } else if (bid < 17408u) { // ---- edge-table build, one edge per thread
    __shared__ int flag32;
    if (tid == 0) flag32 = 0;
    __syncthreads();
    unsigned e = (bid - 16384u) * 256u + tid; // 0..262143
    if (eidx[2u * e + 1u] != 0u) flag32 = 1;  // benign race
    __syncthreads();
    int row, col;
    if (flag32) {
      row = (int)eidx[e];
      col = (int)eidx[e + E_];
    } else {
      const long long* p = (const long long*)eidx;
      row = (int)p[e];
      col = (int)p[e + E_];
    }
    unsigned pos = atomicAdd(ws + CNT_OFF + (unsigned)row, 1u);
    if (pos < 64u) {
      ws[TAB_OFF + ((unsigned)row << 6) + pos] = (unsigned)col;
    } else { // correctness-only spill
      unsigned o = atomicAdd(ws + OVFC_OFF, 1u);
      ws[OVF_OFF + 2u * o]      = (unsigned)row;
      ws[OVF_OFF + 2u * o + 1u] = (unsigned)col;
    }
  } else { // ---- W fp32 -> bf16 transposed (128 blocks)
    unsigned t = (bid - 17408u) * 256u + tid; // 0..32767
    unsigned n = t >> 7, k = t & 127u;
    ((unsigned short*)(ws + WT_OFF))[n * 128u + k] = f2bf(W[k * 256u + n]);
  }
}

// ---------------- kernel 2: full-row table gather-max, dwordx4 (bf16) -----------
// One wave per (batch,row). 64 lanes = 4 edge-groups x 16 lanes; each lane loads
// uint4 (8 channels) -> one wave-load gathers 4 edges x full 128-ch row (1 KB).
// 16-edge inner body keeps 4 independent 1 KB gathers in flight (R2's 8-edge body
// held only 2 -> one ~300cy L2 round trip per 8 edges was the residual stall).
// Column slots pre-loaded into one register/lane (tab is fixed-stride -> one
// coalesced 256 B load, no offs[] indirection) and broadcast per-quad with __shfl.
// EXEC HAZARD (R1 bug, fixed R2): ds_bpermute returns UNDEFINED data when the
// *source* lane is inactive -> every __shfl executes wave-uniform; tail shuffle
// hoisted out of its divergent guard.
// batch = blockIdx&7 -> per-XCD gather slice is the 4 MB x_bf batch slice
// (L2-resident). Max trick: fmax on raw u32 (hi channel; garbage low mantissa
// can't flip a bf16-level compare) and on u<<16 (lo channel, exact).
__global__ __launch_bounds__(256) void k_aggr(const uint4* __restrict__ xbf4,
                                              const unsigned* __restrict__ ws,
                                              uint4* __restrict__ aggr4) {
  const unsigned bi = blockIdx.x;            // 32768 = 4096 rowgroups x 8 batches
  const unsigned b  = bi & 7u;
  const unsigned rg = bi >> 3;               // 0..4095
  const unsigned row = (rg << 2) | (threadIdx.x >> 6); // wave <-> row
  const unsigned lane = threadIdx.x & 63u;
  const unsigned g  = lane >> 4;             // edge subgroup 0..3
  const unsigned ln = lane & 15u;            // uint4 slot within the row
  const unsigned* tab = ws + TAB_OFF;
  const uint4* xb = xbf4 + ((size_t)b << 18); // rows stride 16 uint4

  const unsigned deg = ws[CNT_OFF + row];
  const bool has = (deg != 0u);
  const unsigned d64 = deg < 64u ? deg : 64u;

  // pre-load this row's (up to) 64 column slots; slots >= deg are uninitialized
  // but provably never sourced by a *used* shuffle result.
  const unsigned cpre = tab[(row << 6) + lane];

  float mlo[4], mhi[4];
#pragma unroll
  for (int r = 0; r < 4; ++r) { mlo[r] = -INFINITY; mhi[r] = -INFINITY; }

#define MAX1(a, r)                                                          \
  mhi[r] = fmaxf(mhi[r], __uint_as_float(a));                               \
  mlo[r] = fmaxf(mlo[r], __uint_as_float((a) << 16));
#define MAX2(a, c, r)                                                       \
  mhi[r] = fmaxf(mhi[r], fmaxf(__uint_as_float(a), __uint_as_float(c)));    \
  mlo[r] = fmaxf(mlo[r],                                                    \
      fmaxf(__uint_as_float((a) << 16), __uint_as_float((c) << 16)));

  unsigned t = 0u;
  while (t + 16u <= d64) { // 16 edges/iter: 4 independent 1 KB gathers in flight
    unsigned c0 = (unsigned)__shfl((int)cpre, (int)(t + g));
    unsigned c1 = (unsigned)__shfl((int)cpre, (int)(t + 4u + g));
    unsigned c2 = (unsigned)__shfl((int)cpre, (int)(t + 8u + g));
    unsigned c3 = (unsigned)__shfl((int)cpre, (int)(t + 12u + g));
    uint4 u0 = xb[((size_t)c0 << 4) + ln];
    uint4 u1 = xb[((size_t)c1 << 4) + ln];
    uint4 u2 = xb[((size_t)c2 << 4) + ln];
    uint4 u3 = xb[((size_t)c3 << 4) + ln];
    MAX2(u0.x, u1.x, 0) MAX2(u0.y, u1.y, 1)
    MAX2(u0.z, u1.z, 2) MAX2(u0.w, u1.w, 3)
    MAX2(u2.x, u3.x, 0) MAX2(u2.y, u3.y, 1)
    MAX2(u2.z, u3.z, 2) MAX2(u2.w, u3.w, 3)
    t += 16u;
  }
  if (t + 8u <= d64) { // wave-uniform branch -> full EXEC (safe)
    unsigned c0 = (unsigned)__shfl((int)cpre, (int)(t + g));
    unsigned c1 = (unsigned)__shfl((int)cpre, (int)(t + 4u + g));
    uint4 u0 = xb[((size_t)c0 << 4) + ln];
    uint4 u1 = xb[((size_t)c1 << 4) + ln];
    MAX2(u0.x, u1.x, 0) MAX2(u0.y, u1.y, 1)
    MAX2(u0.z, u1.z, 2) MAX2(u0.w, u1.w, 3)
    t += 8u;
  }
  if (t + 4u <= d64) { // wave-uniform branch -> full EXEC (safe)
    unsigned c = (unsigned)__shfl((int)cpre, (int)(t + g));
    uint4 u = xb[((size_t)c << 4) + ln];
    MAX1(u.x, 0) MAX1(u.y, 1) MAX1(u.z, 2) MAX1(u.w, 3)
    t += 4u;
  }
  {
    // final partial quad (0..3 edges). Shuffle HOISTED out of the divergent
    // guard (R1 lesson): source lane t+g may sit in an inactive group there.
    unsigned rem = d64 - t; // 0..3, wave-uniform
    unsigned c = (unsigned)__shfl((int)cpre, (int)((t + g) & 63u));
    if (g < rem) {
      uint4 u = xb[((size_t)c << 4) + ln];
      MAX1(u.x, 0) MAX1(u.y, 1) MAX1(u.z, 2) MAX1(u.w, 3)
    }
  }
  if (deg > 64u) { // overflow replay: correctness-only, shuffle-free
    unsigned no = ws[OVFC_OFF];
    for (unsigned i = 0u; i < no; i += 4u) {
      unsigned k = i + g;
      if (k < no && ws[OVF_OFF + 2u * k] == row) {
        unsigned c = ws[OVF_OFF + 2u * k + 1u];
        uint4 u = xb[((size_t)c << 4) + ln];
        MAX1(u.x, 0) MAX1(u.y, 1) MAX1(u.z, 2) MAX1(u.w, 3)
      }
    }
  }
#undef MAX1
#undef MAX2

  // reduce the 4 edge-groups (lane bits 4,5); full EXEC here (reconverged)
#pragma unroll
  for (int r = 0; r < 4; ++r) {
    mlo[r] = fmaxf(mlo[r], __shfl_xor(mlo[r], 16, 64));
    mhi[r] = fmaxf(mhi[r], __shfl_xor(mhi[r], 16, 64));
  }
#pragma unroll
  for (int r = 0; r < 4; ++r) {
    mlo[r] = fmaxf(mlo[r], __shfl_xor(mlo[r], 32, 64));
    mhi[r] = fmaxf(mhi[r], __shfl_xor(mhi[r], 32, 64));
  }

  if (g == 0u) {
    const uint4 xw = xb[((size_t)row << 4) + ln];
    unsigned xv[4] = {xw.x, xw.y, xw.z, xw.w};
    unsigned ox[4];
#pragma unroll
    for (int r = 0; r < 4; ++r) {
      float vlo = has ? mlo[r] : 0.0f;
      float vhi = has ? __uint_as_float(__float_as_uint(mhi[r]) & 0xFFFF0000u)
                      : 0.0f;
      unsigned lo = f2bf(vlo - __uint_as_float(xv[r] << 16));
      unsigned hi = f2bf(vhi - __uint_as_float(xv[r] & 0xFFFF0000u));
      ox[r] = lo | (hi << 16);
    }
    uint4 o = {ox[0], ox[1], ox[2], ox[3]};
    aggr4[(((size_t)b << 14) + row) * 16u + ln] = o;
  }
}

// ---------------- kernel 3: aggr(bf16) @ Wt(bf16) + b, exact GELU ---------------
// A-fragments read directly from global (no intra-block A reuse; the 4 unrolled
// kc loads cover full 64B lines per row). LDS = Wt only -> 4 blocks/CU.
__global__ __launch_bounds__(256, 4) void k_gemm(const unsigned short* __restrict__ aggr,
                                                 const unsigned short* __restrict__ Wt,
                                                 const float* __restrict__ bias,
                                                 float* __restrict__ out) {
  __shared__ unsigned short Wt_sm[128 * 136]; // 34816 B; stride 136 (2-way free)
  const int tid = threadIdx.x;
  const int nbase = blockIdx.x * 128; // n-tiles adjacent in dispatch: A re-read
  const int mbase = blockIdx.y * 64;  // of the same m-tile stays cache-warm

#pragma unroll
  for (int i = 0; i < 8; ++i) {
    int slot = i * 256 + tid;
    int n = slot >> 4, k8 = slot & 15;
    uint4 u = *(const uint4*)(Wt + (size_t)(nbase + n) * 128 + k8 * 8);
    *(uint4*)&Wt_sm[n * 136 + k8 * 8] = u;
  }
  __syncthreads();

  const int lane = tid & 63;
  const int wv = tid >> 6;   // wave id: rows [wv*16, wv*16+16)
  const int ln = lane & 15;
  const int q = lane >> 4;   // quad

  // A-operand: A[m = lane&15][k = quad*8 + j] -> 16B contiguous in global
  const unsigned short* arow = aggr + (size_t)(mbase + wv * 16 + ln) * 128 + q * 8;
  bf16x8 af[4];
#pragma unroll
  for (int kc = 0; kc < 4; ++kc) af[kc] = *(const bf16x8*)(arow + kc * 32);

  f32x4 acc[8];
#pragma unroll
  for (int f = 0; f < 8; ++f) acc[f] = (f32x4){0.f, 0.f, 0.f, 0.f};

#pragma unroll
  for (int kc = 0; kc < 4; ++kc) {
#pragma unroll
    for (int f = 0; f < 8; ++f) {
      // B-operand: B[k = quad*8 + j][n = lane&15] contiguous in Wt[n][k]
      bf16x8 bf = *(const bf16x8*)&Wt_sm[(f * 16 + ln) * 136 + kc * 32 + q * 8];
      acc[f] = __builtin_amdgcn_mfma_f32_16x16x32_bf16(af[kc], bf, acc[f], 0, 0, 0);
    }
  }

  // Epilogue: C/D layout col = lane&15, row = quad*4 + reg (m89-verified)
#pragma unroll
  for (int f = 0; f < 8; ++f) {
    int n = nbase + f * 16 + ln;
    float bv = bias[n];
#pragma unroll
    for (int r = 0; r < 4; ++r) {
      int m = mbase + wv * 16 + q * 4 + r;
      out[(size_t)m * 256 + n] = gelu_exact(acc[f][r] + bv);
    }
  }
}

extern "C" void kernel_launch(void* const* d_in, const int* in_sizes, int n_in,
                              void* d_out, int out_size, void* d_ws, size_t ws_size,
                              hipStream_t stream) {
  const float* x      = (const float*)d_in[0];
  const unsigned* eid = (const unsigned*)d_in[1];
  const float* W      = (const float*)d_in[2];
  const float* bia    = (const float*)d_in[3];
  float* out          = (float*)d_out;
  unsigned* ws        = (unsigned*)d_ws;

  unsigned short* Wt   = (unsigned short*)(ws + WT_OFF);
  unsigned short* aggr = (unsigned short*)(ws + AGGR_OFF);

  // zero cnt[16384] + ovf_cnt (+pad)
  hipMemsetAsync(ws + CNT_OFF, 0, 16448 * sizeof(unsigned), stream);
  hipLaunchKernelGGL(k_prep, dim3(17536),   dim3(256), 0, stream, x, eid, W, ws);
  hipLaunchKernelGGL(k_aggr, dim3(32768),   dim3(256), 0, stream,
                     (const uint4*)(ws + XBF_OFF), ws, (uint4*)(ws + AGGR_OFF));
  hipLaunchKernelGGL(k_gemm, dim3(2, 2048), dim3(256), 0, stream,
                     aggr, Wt, bia, out);
}